// Round 10
// baseline (22918.123 us; speedup 1.0000x reference)
//
#include <hip/hip_runtime.h>

typedef unsigned int u32;
typedef long long i64;

#define IN_F 4096
#define OUT_F 4096
#define NW ((i64)IN_F * OUT_F)   // 16777216 elements

// ---------------------------------------------------------------------------
// Round 10: straight f32 interpretation (R9-proven: all float buffers are f32;
// harness upcast the 16-bit sources). Mimic the reference numerics exactly:
//   out = f32( f16round( f16(x) @ W^T ) ) + x @ Wo^T
// with Wo = scatter_add(vals) in f32. Naive VALU GEMM - correctness round.
// ---------------------------------------------------------------------------

__global__ __launch_bounds__(256) void zero_f32(float* __restrict__ p, i64 n) {
  i64 i = (i64)blockIdx.x * blockDim.x + threadIdx.x;
  i64 s = (i64)gridDim.x * blockDim.x;
  for (i64 j = i; j < n; j += s) p[j] = 0.0f;
}

__global__ __launch_bounds__(256) void scatter_wo(
    const float* __restrict__ vals, const int* __restrict__ rows,
    const int* __restrict__ cols, float* __restrict__ wo, int nnz) {
  int i = blockIdx.x * blockDim.x + threadIdx.x;
  if (i >= nnz) return;
  int r = rows[i], c = cols[i];
  if (r < 0 || r >= OUT_F || c < 0 || c >= IN_F) return;
  atomicAdd(&wo[(size_t)r * IN_F + c], vals[i]);
}

// Two-stream GEMM. Block (64,4): lane tx -> output col n, ty -> 16-row m group.
// accB: fp16-rounded x (RNE) * W, f32 accum  (= jax f16 matmul w/ f32 compute)
// accO: raw f32 x * Wo
// epilogue: out = f32(f16(accB)) + accO      (= reference's .astype chain)
__global__ __launch_bounds__(256) void gemm2(
    const float* __restrict__ x, const float* __restrict__ W,
    const float* __restrict__ Wo, float* __restrict__ out, int M) {
  const int n  = blockIdx.x * 64 + threadIdx.x;
  const int m0 = blockIdx.y * 64 + threadIdx.y * 16;
  const float* wr = W  + (size_t)n * IN_F;
  const float* wo = Wo + (size_t)n * IN_F;

  float accB[16], accO[16];
#pragma unroll
  for (int j = 0; j < 16; ++j) { accB[j] = 0.0f; accO[j] = 0.0f; }

  for (int k = 0; k < IN_F; k += 8) {
    float4 wa = *(const float4*)(wr + k);
    float4 wb = *(const float4*)(wr + k + 4);
    float4 oa = *(const float4*)(wo + k);
    float4 ob = *(const float4*)(wo + k + 4);
#pragma unroll
    for (int j = 0; j < 16; ++j) {
      const float* xr = x + (size_t)(m0 + j) * IN_F + k;
      float4 xa = *(const float4*)xr;
      float4 xb = *(const float4*)(xr + 4);
      // fp16-rounded copies (RNE round trip) for the base stream
      float h0 = (float)(_Float16)xa.x, h1 = (float)(_Float16)xa.y;
      float h2 = (float)(_Float16)xa.z, h3 = (float)(_Float16)xa.w;
      float h4 = (float)(_Float16)xb.x, h5 = (float)(_Float16)xb.y;
      float h6 = (float)(_Float16)xb.z, h7 = (float)(_Float16)xb.w;
      accB[j] += h0 * wa.x + h1 * wa.y + h2 * wa.z + h3 * wa.w
               + h4 * wb.x + h5 * wb.y + h6 * wb.z + h7 * wb.w;
      accO[j] += xa.x * oa.x + xa.y * oa.y + xa.z * oa.z + xa.w * oa.w
               + xb.x * ob.x + xb.y * ob.y + xb.z * ob.z + xb.w * ob.w;
    }
  }

#pragma unroll
  for (int j = 0; j < 16; ++j)
    out[(size_t)(m0 + j) * OUT_F + n] = (float)(_Float16)accB[j] + accO[j];
}

// Base-only fallback (no workspace): still interpretable on failure.
__global__ __launch_bounds__(256) void gemm_base(
    const float* __restrict__ x, const float* __restrict__ W,
    float* __restrict__ out, int M) {
  const int n  = blockIdx.x * 64 + threadIdx.x;
  const int m0 = blockIdx.y * 64 + threadIdx.y * 16;
  const float* wr = W + (size_t)n * IN_F;
  float accB[16];
#pragma unroll
  for (int j = 0; j < 16; ++j) accB[j] = 0.0f;
  for (int k = 0; k < IN_F; k += 8) {
    float4 wa = *(const float4*)(wr + k);
    float4 wb = *(const float4*)(wr + k + 4);
#pragma unroll
    for (int j = 0; j < 16; ++j) {
      const float* xr = x + (size_t)(m0 + j) * IN_F + k;
      float4 xa = *(const float4*)xr;
      float4 xb = *(const float4*)(xr + 4);
      accB[j] += (float)(_Float16)xa.x * wa.x + (float)(_Float16)xa.y * wa.y
               + (float)(_Float16)xa.z * wa.z + (float)(_Float16)xa.w * wa.w
               + (float)(_Float16)xb.x * wb.x + (float)(_Float16)xb.y * wb.y
               + (float)(_Float16)xb.z * wb.z + (float)(_Float16)xb.w * wb.w;
    }
  }
#pragma unroll
  for (int j = 0; j < 16; ++j)
    out[(size_t)(m0 + j) * OUT_F + n] = (float)(_Float16)accB[j];
}

// ---------------------------------------------------------------------------
extern "C" void kernel_launch(void* const* d_in, const int* in_sizes, int n_in,
                              void* d_out, int out_size, void* d_ws, size_t ws_size,
                              hipStream_t stream) {
  const float* x    = (const float*)d_in[0];
  const float* W    = (const float*)d_in[1];
  const float* vals = (const float*)d_in[2];
  const int*   rows = (const int*)d_in[3];
  const int*   cols = (const int*)d_in[4];
  float*       out  = (float*)d_out;

  const i64 total_x = (i64)in_sizes[0];
  const int M   = (int)(total_x / IN_F);    // 8192
  const int nnz = in_sizes[2];              // 167772
  if (M <= 0 || M % 64 != 0) return;

  const dim3 grid(OUT_F / 64, M / 64), blk(64, 4);

  if (ws_size >= (size_t)NW * 4) {
    float* wo = (float*)d_ws;
    zero_f32<<<2048, 256, 0, stream>>>(wo, NW);
    scatter_wo<<<(nnz + 255) / 256, 256, 0, stream>>>(vals, rows, cols, wo, nnz);
    gemm2<<<grid, blk, 0, stream>>>(x, W, wo, out, M);
  } else {
    gemm_base<<<grid, blk, 0, stream>>>(x, W, out, M);
  }
}

// Round 11
// 1375.903 us; speedup vs baseline: 16.6568x; 16.6568x over previous
//
#include <hip/hip_runtime.h>

typedef _Float16 f16;
typedef unsigned short u16;
typedef unsigned int u32;
typedef long long i64;
typedef __attribute__((ext_vector_type(8))) _Float16 f16x8;
typedef __attribute__((ext_vector_type(4))) float f32x4;

#define IN_F 4096
#define OUT_F 4096

__device__ __forceinline__ void gload16(const f16* g, f16* l) {
  __builtin_amdgcn_global_load_lds(
      (const __attribute__((address_space(1))) void*)g,
      (__attribute__((address_space(3))) void*)l, 16, 0, 0);
}

// ---------------------------------------------------------------------------
// f32 -> f16 convert (16B stores)
// ---------------------------------------------------------------------------
__global__ __launch_bounds__(256) void cvt_f32_f16(
    const float* __restrict__ in, f16* __restrict__ out, i64 n8) {
  i64 s = (i64)gridDim.x * blockDim.x;
  for (i64 j = (i64)blockIdx.x * blockDim.x + threadIdx.x; j < n8; j += s) {
    float4 a = ((const float4*)in)[2 * j];
    float4 b = ((const float4*)in)[2 * j + 1];
    f16x8 o;
    o[0] = (f16)a.x; o[1] = (f16)a.y; o[2] = (f16)a.z; o[3] = (f16)a.w;
    o[4] = (f16)b.x; o[5] = (f16)b.y; o[6] = (f16)b.z; o[7] = (f16)b.w;
    ((f16x8*)out)[j] = o;
  }
}

__global__ __launch_bounds__(256) void zero32(u32* __restrict__ p, i64 n) {
  i64 s = (i64)gridDim.x * blockDim.x;
  for (i64 j = (i64)blockIdx.x * blockDim.x + threadIdx.x; j < n; j += s) p[j] = 0u;
}

// scatter-add f32 vals into f16 dense Wo via 32-bit CAS (handles duplicates)
__global__ __launch_bounds__(256) void scatter_woh(
    const float* __restrict__ vals, const int* __restrict__ rows,
    const int* __restrict__ cols, f16* __restrict__ woh, int nnz) {
  int i = blockIdx.x * blockDim.x + threadIdx.x;
  if (i >= nnz) return;
  int r = rows[i], c = cols[i];
  if (r < 0 || r >= OUT_F || c < 0 || c >= IN_F) return;
  float v = vals[i];
  size_t idx = (size_t)r * IN_F + c;
  u32* p = (u32*)woh + (idx >> 1);
  u32 sh = (u32)(idx & 1) * 16u;
  union { f16 h; u16 u; } cv;
  u32 old = *p;
  while (true) {
    u32 assumed = old;
    cv.u = (u16)((assumed >> sh) & 0xFFFFu);
    float cur = (float)cv.h;
    cv.h = (f16)(cur + v);
    u32 nw = (assumed & ~(0xFFFFu << sh)) | ((u32)cv.u << sh);
    old = atomicCAS(p, assumed, nw);
    if (old == assumed) break;
  }
}

// ---------------------------------------------------------------------------
// Fused two-stream MFMA GEMM (m97 structure).
//   accB = f16(x) @ Wh^T   (f32 accum)  -> f16-rounded (reference semantics)
//   accO = f16(x) @ Oh^T   (f32 accum)
//   out  = f32(f16(accB)) + accO
// A16: A staged via global_load_lds from precomputed xh; else reg-staged
// f32->f16 with +8 f16 row pad (LDA=40) to spread ds_write banks.
// ---------------------------------------------------------------------------
template <bool A16>
__global__ __launch_bounds__(256) void gemm_fused(
    const float* __restrict__ Xf, const f16* __restrict__ Xh,
    const f16* __restrict__ Wh, const f16* __restrict__ Oh,
    float* __restrict__ out, int M) {
  constexpr int LDA = A16 ? 32 : 40;
  __shared__ alignas(16) f16 As[128 * LDA];
  __shared__ alignas(16) f16 Ws[128 * 32];
  __shared__ alignas(16) f16 Os[128 * 32];

  const int tid = threadIdx.x, lane = tid & 63, wave = tid >> 6;
  const int wr = wave >> 1, wc = wave & 1;

  const int nbn = OUT_F / 128;                       // 32
  const int nwg = (int)gridDim.x;
  const int bid = (int)blockIdx.x;
  const int swz = ((nwg & 7) == 0) ? ((bid & 7) * (nwg >> 3) + (bid >> 3)) : bid;
  const int brow = (swz / nbn) << 7;
  const int bcol = (swz % nbn) << 7;

  f32x4 accB[4][4] = {}, accO[4][4] = {};

  // staging decomposition: thread t covers rows (t>>2) and (t>>2)+64, k-seg (t&3)*8
  const int srow = tid >> 2, sk = (tid & 3) * 8;
  const f16* gW = Wh + (size_t)(bcol + srow) * IN_F + sk;
  const f16* gO = Oh + (size_t)(bcol + srow) * IN_F + sk;
  f16* sW = Ws + tid * 8;
  f16* sO = Os + tid * 8;

  const f16*   gA = A16 ? (Xh + (size_t)(brow + srow) * IN_F + sk) : (const f16*)nullptr;
  const float* gX = A16 ? (const float*)nullptr : (Xf + (size_t)(brow + srow) * IN_F + sk);
  f16* sA  = As + tid * 8;                 // A16 linear dest
  f16* sAr = As + srow * LDA + sk;         // padded reg-staging dest

  const f16* pa = As + (wr * 64 + (lane & 15)) * LDA + (lane >> 4) * 8;
  const f16* pw = Ws + (wc * 64 + (lane & 15)) * 32 + (lane >> 4) * 8;
  const f16* po = Os + (wc * 64 + (lane & 15)) * 32 + (lane >> 4) * 8;

  for (int k0 = 0; k0 < IN_F; k0 += 32) {
    if constexpr (A16) {
      gload16(gA + k0, sA);
      gload16(gA + k0 + (size_t)64 * IN_F, sA + 2048);
    } else {
      float4 u0 = *(const float4*)(gX + k0);
      float4 u1 = *(const float4*)(gX + k0 + 4);
      float4 v0 = *(const float4*)(gX + k0 + (size_t)64 * IN_F);
      float4 v1 = *(const float4*)(gX + k0 + (size_t)64 * IN_F + 4);
      f16x8 h0, h1;
      h0[0] = (f16)u0.x; h0[1] = (f16)u0.y; h0[2] = (f16)u0.z; h0[3] = (f16)u0.w;
      h0[4] = (f16)u1.x; h0[5] = (f16)u1.y; h0[6] = (f16)u1.z; h0[7] = (f16)u1.w;
      h1[0] = (f16)v0.x; h1[1] = (f16)v0.y; h1[2] = (f16)v0.z; h1[3] = (f16)v0.w;
      h1[4] = (f16)v1.x; h1[5] = (f16)v1.y; h1[6] = (f16)v1.z; h1[7] = (f16)v1.w;
      *(f16x8*)sAr = h0;
      *(f16x8*)(sAr + 64 * LDA) = h1;
    }
    gload16(gW + k0, sW);
    gload16(gW + k0 + (size_t)64 * IN_F, sW + 2048);
    gload16(gO + k0, sO);
    gload16(gO + k0 + (size_t)64 * IN_F, sO + 2048);
    __syncthreads();   // drains vmcnt+lgkmcnt: tiles ready

    f16x8 af[4], wf[4], of[4];
#pragma unroll
    for (int m = 0; m < 4; ++m) af[m] = *(const f16x8*)(pa + m * 16 * LDA);
#pragma unroll
    for (int n = 0; n < 4; ++n) {
      wf[n] = *(const f16x8*)(pw + n * 512);
      of[n] = *(const f16x8*)(po + n * 512);
    }
#pragma unroll
    for (int m = 0; m < 4; ++m)
#pragma unroll
      for (int n = 0; n < 4; ++n) {
        accB[m][n] = __builtin_amdgcn_mfma_f32_16x16x32_f16(af[m], wf[n], accB[m][n], 0, 0, 0);
        accO[m][n] = __builtin_amdgcn_mfma_f32_16x16x32_f16(af[m], of[n], accO[m][n], 0, 0, 0);
      }
    __syncthreads();   // protect LDS before next stage
  }

  // C/D: col = lane&15, row = (lane>>4)*4 + r  (m89-verified, dtype-indep)
  const int crow0 = brow + wr * 64 + ((lane >> 4) << 2);
  const int ccol0 = bcol + wc * 64 + (lane & 15);
#pragma unroll
  for (int m = 0; m < 4; ++m)
#pragma unroll
    for (int n = 0; n < 4; ++n)
#pragma unroll
      for (int r = 0; r < 4; ++r)
        out[(size_t)(crow0 + m * 16 + r) * OUT_F + (ccol0 + n * 16)] =
            (float)(f16)accB[m][n][r] + accO[m][n][r];
}

// ---------------------------------------------------------------------------
extern "C" void kernel_launch(void* const* d_in, const int* in_sizes, int n_in,
                              void* d_out, int out_size, void* d_ws, size_t ws_size,
                              hipStream_t stream) {
  const float* x    = (const float*)d_in[0];
  const float* W    = (const float*)d_in[1];
  const float* vals = (const float*)d_in[2];
  const int*   rows = (const int*)d_in[3];
  const int*   cols = (const int*)d_in[4];
  float*       out  = (float*)d_out;

  const i64 total_x = (i64)in_sizes[0];
  const int M   = (int)(total_x / IN_F);            // 8192
  const int nnz = in_sizes[2];
  if (M <= 0 || M % 128 != 0) return;

  const size_t whb = (size_t)OUT_F * IN_F * 2;      // 32 MB
  const size_t xhb = (size_t)M * IN_F * 2;          // 64 MB
  const int grid = (M / 128) * (OUT_F / 128);       // 2048

  if (ws_size >= xhb + 2 * whb) {
    // FULL: xh + wh + woh, all staging via global_load_lds
    f16* xh  = (f16*)d_ws;
    f16* wh  = (f16*)((char*)d_ws + xhb);
    f16* woh = (f16*)((char*)d_ws + xhb + whb);
    cvt_f32_f16<<<2048, 256, 0, stream>>>(x, xh, total_x / 8);
    cvt_f32_f16<<<2048, 256, 0, stream>>>(W, wh, (i64)OUT_F * IN_F / 8);
    zero32<<<2048, 256, 0, stream>>>((u32*)woh, (i64)(whb / 4));
    scatter_woh<<<(nnz + 255) / 256, 256, 0, stream>>>(vals, rows, cols, woh, nnz);
    gemm_fused<true><<<grid, 256, 0, stream>>>(nullptr, xh, wh, woh, out, M);
  } else if (ws_size >= 2 * whb) {
    // HALF (proven >=64MB): wh + woh; A reg-staged f32->f16
    f16* wh  = (f16*)d_ws;
    f16* woh = (f16*)((char*)d_ws + whb);
    cvt_f32_f16<<<2048, 256, 0, stream>>>(W, wh, (i64)OUT_F * IN_F / 8);
    zero32<<<2048, 256, 0, stream>>>((u32*)woh, (i64)(whb / 4));
    scatter_woh<<<(nnz + 255) / 256, 256, 0, stream>>>(vals, rows, cols, woh, nnz);
    gemm_fused<false><<<grid, 256, 0, stream>>>(x, nullptr, wh, woh, out, M);
  }
}

// Round 12
// 741.657 us; speedup vs baseline: 30.9012x; 1.8552x over previous
//
#include <hip/hip_runtime.h>

typedef _Float16 f16;
typedef unsigned short u16;
typedef unsigned int u32;
typedef long long i64;
typedef __attribute__((ext_vector_type(8))) _Float16 f16x8;
typedef __attribute__((ext_vector_type(4))) float f32x4;

#define IN_F 4096
#define OUT_F 4096

__device__ __forceinline__ void gload16(const f16* g, f16* l) {
  __builtin_amdgcn_global_load_lds(
      (const __attribute__((address_space(1))) void*)g,
      (__attribute__((address_space(3))) void*)l, 16, 0, 0);
}

// ---------------------------------------------------------------------------
// f32 -> f16 convert (16B stores)
// ---------------------------------------------------------------------------
__global__ __launch_bounds__(256) void cvt_f32_f16(
    const float* __restrict__ in, f16* __restrict__ out, i64 n8) {
  i64 s = (i64)gridDim.x * blockDim.x;
  for (i64 j = (i64)blockIdx.x * blockDim.x + threadIdx.x; j < n8; j += s) {
    float4 a = ((const float4*)in)[2 * j];
    float4 b = ((const float4*)in)[2 * j + 1];
    f16x8 o;
    o[0] = (f16)a.x; o[1] = (f16)a.y; o[2] = (f16)a.z; o[3] = (f16)a.w;
    o[4] = (f16)b.x; o[5] = (f16)b.y; o[6] = (f16)b.z; o[7] = (f16)b.w;
    ((f16x8*)out)[j] = o;
  }
}

__global__ __launch_bounds__(256) void zero32(u32* __restrict__ p, i64 n) {
  i64 s = (i64)gridDim.x * blockDim.x;
  for (i64 j = (i64)blockIdx.x * blockDim.x + threadIdx.x; j < n; j += s) p[j] = 0u;
}

// scatter-add f32 vals into f16 dense Wo via 32-bit CAS (handles duplicates)
__global__ __launch_bounds__(256) void scatter_woh(
    const float* __restrict__ vals, const int* __restrict__ rows,
    const int* __restrict__ cols, f16* __restrict__ woh, int nnz) {
  int i = blockIdx.x * blockDim.x + threadIdx.x;
  if (i >= nnz) return;
  int r = rows[i], c = cols[i];
  if (r < 0 || r >= OUT_F || c < 0 || c >= IN_F) return;
  float v = vals[i];
  size_t idx = (size_t)r * IN_F + c;
  u32* p = (u32*)woh + (idx >> 1);
  u32 sh = (u32)(idx & 1) * 16u;
  union { f16 h; u16 u; } cv;
  u32 old = *p;
  while (true) {
    u32 assumed = old;
    cv.u = (u16)((assumed >> sh) & 0xFFFFu);
    float cur = (float)cv.h;
    cv.h = (f16)(cur + v);
    u32 nw = (assumed & ~(0xFFFFu << sh)) | ((u32)cv.u << sh);
    old = atomicCAS(p, assumed, nw);
    if (old == assumed) break;
  }
}

// ---------------------------------------------------------------------------
// Single-stream m97-structure GEMM: acc = f16(x) @ B^T (f32 accum).
// STREAM 0 (base):  out  = f32(f16(acc))   [reference's f16 output rounding]
// STREAM 1 (ortho): out += acc             [block-owned region; race-free]
// A16: A staged via global_load_lds from xh; else reg-staged f32->f16 (LDA=40).
// __launch_bounds__(256,2): pin allocator to <=256 VGPR -> 2 waves/SIMD.
// ---------------------------------------------------------------------------
template <bool A16, int STREAM>
__global__ __launch_bounds__(256, 2) void gemm_one(
    const float* __restrict__ Xf, const f16* __restrict__ Xh,
    const f16* __restrict__ Bm, float* __restrict__ out, int M) {
  constexpr int LDA = A16 ? 32 : 40;
  __shared__ alignas(16) f16 As[128 * LDA];
  __shared__ alignas(16) f16 Bs[128 * 32];

  const int tid = threadIdx.x, lane = tid & 63, wave = tid >> 6;
  const int wr = wave >> 1, wc = wave & 1;

  const int nbn = OUT_F / 128;                       // 32
  const int nwg = (int)gridDim.x;
  const int bid = (int)blockIdx.x;
  const int swz = ((nwg & 7) == 0) ? ((bid & 7) * (nwg >> 3) + (bid >> 3)) : bid;
  const int brow = (swz / nbn) << 7;
  const int bcol = (swz % nbn) << 7;

  f32x4 acc[4][4] = {};

  const int srow = tid >> 2, sk = (tid & 3) * 8;
  const f16* gB = Bm + (size_t)(bcol + srow) * IN_F + sk;
  f16* sB = Bs + tid * 8;

  const f16*   gA = A16 ? (Xh + (size_t)(brow + srow) * IN_F + sk) : (const f16*)nullptr;
  const float* gX = A16 ? (const float*)nullptr : (Xf + (size_t)(brow + srow) * IN_F + sk);
  f16* sA  = As + tid * 8;                 // A16 linear dest
  f16* sAr = As + srow * LDA + sk;         // padded reg-staging dest

  const f16* pa = As + (wr * 64 + (lane & 15)) * LDA + (lane >> 4) * 8;
  const f16* pb = Bs + (wc * 64 + (lane & 15)) * 32 + (lane >> 4) * 8;

  for (int k0 = 0; k0 < IN_F; k0 += 32) {
    if constexpr (A16) {
      gload16(gA + k0, sA);
      gload16(gA + k0 + (size_t)64 * IN_F, sA + 2048);
    } else {
      float4 u0 = *(const float4*)(gX + k0);
      float4 u1 = *(const float4*)(gX + k0 + 4);
      float4 v0 = *(const float4*)(gX + k0 + (size_t)64 * IN_F);
      float4 v1 = *(const float4*)(gX + k0 + (size_t)64 * IN_F + 4);
      f16x8 h0, h1;
      h0[0] = (f16)u0.x; h0[1] = (f16)u0.y; h0[2] = (f16)u0.z; h0[3] = (f16)u0.w;
      h0[4] = (f16)u1.x; h0[5] = (f16)u1.y; h0[6] = (f16)u1.z; h0[7] = (f16)u1.w;
      h1[0] = (f16)v0.x; h1[1] = (f16)v0.y; h1[2] = (f16)v0.z; h1[3] = (f16)v0.w;
      h1[4] = (f16)v1.x; h1[5] = (f16)v1.y; h1[6] = (f16)v1.z; h1[7] = (f16)v1.w;
      *(f16x8*)sAr = h0;
      *(f16x8*)(sAr + 64 * LDA) = h1;
    }
    gload16(gB + k0, sB);
    gload16(gB + k0 + (size_t)64 * IN_F, sB + 2048);
    __syncthreads();   // drains vmcnt+lgkmcnt: tiles ready

    f16x8 af[4], bf[4];
#pragma unroll
    for (int m = 0; m < 4; ++m) af[m] = *(const f16x8*)(pa + m * 16 * LDA);
#pragma unroll
    for (int n = 0; n < 4; ++n) bf[n] = *(const f16x8*)(pb + n * 512);
#pragma unroll
    for (int m = 0; m < 4; ++m)
#pragma unroll
      for (int n = 0; n < 4; ++n)
        acc[m][n] = __builtin_amdgcn_mfma_f32_16x16x32_f16(af[m], bf[n], acc[m][n], 0, 0, 0);
    __syncthreads();   // protect LDS before next stage
  }

  // C/D: col = lane&15, row = (lane>>4)*4 + r  (m89-verified)
  const int crow0 = brow + wr * 64 + ((lane >> 4) << 2);
  const int ccol0 = bcol + wc * 64 + (lane & 15);
#pragma unroll
  for (int m = 0; m < 4; ++m)
#pragma unroll
    for (int n = 0; n < 4; ++n)
#pragma unroll
      for (int r = 0; r < 4; ++r) {
        float* p = out + (size_t)(crow0 + m * 16 + r) * OUT_F + (ccol0 + n * 16);
        if constexpr (STREAM == 0)
          *p = (float)(f16)acc[m][n][r];
        else
          *p += acc[m][n][r];
      }
}

// ---------------------------------------------------------------------------
extern "C" void kernel_launch(void* const* d_in, const int* in_sizes, int n_in,
                              void* d_out, int out_size, void* d_ws, size_t ws_size,
                              hipStream_t stream) {
  const float* x    = (const float*)d_in[0];
  const float* W    = (const float*)d_in[1];
  const float* vals = (const float*)d_in[2];
  const int*   rows = (const int*)d_in[3];
  const int*   cols = (const int*)d_in[4];
  float*       out  = (float*)d_out;

  const i64 total_x = (i64)in_sizes[0];
  const int M   = (int)(total_x / IN_F);            // 8192
  const int nnz = in_sizes[2];
  if (M <= 0 || M % 128 != 0) return;

  const size_t whb = (size_t)OUT_F * IN_F * 2;      // 32 MB
  const size_t xhb = (size_t)M * IN_F * 2;          // 64 MB
  const int grid = (M / 128) * (OUT_F / 128);       // 2048

  if (ws_size >= xhb + 2 * whb) {
    // FULL: xh + wh + woh; all staging via global_load_lds
    f16* xh  = (f16*)d_ws;
    f16* wh  = (f16*)((char*)d_ws + xhb);
    f16* woh = (f16*)((char*)d_ws + xhb + whb);
    cvt_f32_f16<<<2048, 256, 0, stream>>>(x, xh, total_x / 8);
    cvt_f32_f16<<<2048, 256, 0, stream>>>(W, wh, (i64)OUT_F * IN_F / 8);
    zero32<<<2048, 256, 0, stream>>>((u32*)woh, (i64)(whb / 4));
    scatter_woh<<<(nnz + 255) / 256, 256, 0, stream>>>(vals, rows, cols, woh, nnz);
    gemm_one<true, 0><<<grid, 256, 0, stream>>>(nullptr, xh, wh, out, M);
    gemm_one<true, 1><<<grid, 256, 0, stream>>>(nullptr, xh, woh, out, M);
  } else if (ws_size >= 2 * whb) {
    // HALF (>=64MB proven): wh + woh; A reg-staged f32->f16 in both passes
    f16* wh  = (f16*)d_ws;
    f16* woh = (f16*)((char*)d_ws + whb);
    cvt_f32_f16<<<2048, 256, 0, stream>>>(W, wh, (i64)OUT_F * IN_F / 8);
    zero32<<<2048, 256, 0, stream>>>((u32*)woh, (i64)(whb / 4));
    scatter_woh<<<(nnz + 255) / 256, 256, 0, stream>>>(vals, rows, cols, woh, nnz);
    gemm_one<false, 0><<<grid, 256, 0, stream>>>(x, nullptr, wh, out, M);
    gemm_one<false, 1><<<grid, 256, 0, stream>>>(x, nullptr, woh, out, M);
  }
}

// Round 13
// 656.917 us; speedup vs baseline: 34.8874x; 1.1290x over previous
//
#include <hip/hip_runtime.h>

typedef _Float16 f16;
typedef unsigned short u16;
typedef unsigned int u32;
typedef long long i64;
typedef __attribute__((ext_vector_type(8))) _Float16 f16x8;
typedef __attribute__((ext_vector_type(4))) float f32x4;

#define IN_F 4096
#define OUT_F 4096

__device__ __forceinline__ void gload16(const f16* g, f16* l) {
  __builtin_amdgcn_global_load_lds(
      (const __attribute__((address_space(1))) void*)g,
      (__attribute__((address_space(3))) void*)l, 16, 0, 0);
}

// ---------------------------------------------------------------------------
// prep kernels (unchanged from R12)
// ---------------------------------------------------------------------------
__global__ __launch_bounds__(256) void cvt_f32_f16(
    const float* __restrict__ in, f16* __restrict__ out, i64 n8) {
  i64 s = (i64)gridDim.x * blockDim.x;
  for (i64 j = (i64)blockIdx.x * blockDim.x + threadIdx.x; j < n8; j += s) {
    float4 a = ((const float4*)in)[2 * j];
    float4 b = ((const float4*)in)[2 * j + 1];
    f16x8 o;
    o[0] = (f16)a.x; o[1] = (f16)a.y; o[2] = (f16)a.z; o[3] = (f16)a.w;
    o[4] = (f16)b.x; o[5] = (f16)b.y; o[6] = (f16)b.z; o[7] = (f16)b.w;
    ((f16x8*)out)[j] = o;
  }
}

__global__ __launch_bounds__(256) void zero32(u32* __restrict__ p, i64 n) {
  i64 s = (i64)gridDim.x * blockDim.x;
  for (i64 j = (i64)blockIdx.x * blockDim.x + threadIdx.x; j < n; j += s) p[j] = 0u;
}

__global__ __launch_bounds__(256) void scatter_woh(
    const float* __restrict__ vals, const int* __restrict__ rows,
    const int* __restrict__ cols, f16* __restrict__ woh, int nnz) {
  int i = blockIdx.x * blockDim.x + threadIdx.x;
  if (i >= nnz) return;
  int r = rows[i], c = cols[i];
  if (r < 0 || r >= OUT_F || c < 0 || c >= IN_F) return;
  float v = vals[i];
  size_t idx = (size_t)r * IN_F + c;
  u32* p = (u32*)woh + (idx >> 1);
  u32 sh = (u32)(idx & 1) * 16u;
  union { f16 h; u16 u; } cv;
  u32 old = *p;
  while (true) {
    u32 assumed = old;
    cv.u = (u16)((assumed >> sh) & 0xFFFFu);
    float cur = (float)cv.h;
    cv.h = (f16)(cur + v);
    u32 nw = (assumed & ~(0xFFFFu << sh)) | ((u32)cv.u << sh);
    old = atomicCAS(p, assumed, nw);
    if (old == assumed) break;
  }
}

// ---------------------------------------------------------------------------
// 256x256 8-phase GEMM (T2 swizzle + T3/T4 counted pipeline + T5 setprio).
// acc = f16(x) @ B^T, f32 accum.  STREAM 0: out = f32(f16(acc));  1: out += acc.
// LDS: A,B tiles [2 dbuf][256 rows][64 f16], 128 KiB.  8 waves (2M x 4N),
// per-wave 128x64 out = acc[8][4].  Swizzle: 16B chunk slot = raw ^ (row&7),
// applied on the GLOBAL source (gload_lds dest lane-linear) and on ds_read.
// ---------------------------------------------------------------------------
template <int STREAM>
__global__ __launch_bounds__(512, 2) void gemm_256(
    const f16* __restrict__ Xh, const f16* __restrict__ Bm,
    float* __restrict__ out, int M) {
  __shared__ alignas(16) f16 As[2][16384];
  __shared__ alignas(16) f16 Bs[2][16384];

  const int tid = threadIdx.x;
  const int lane = tid & 63;
  const int wave = tid >> 6;
  const int wr = wave >> 2;         // 0..1  (M half)
  const int wc = wave & 3;          // 0..3  (N quarter)
  const int lo = lane & 15, hi = lane >> 4, l7 = lane & 7;

  const int bid = (int)blockIdx.x;
  const int nbn = OUT_F / 256;                      // 16
  const int nwg = (M / 256) * nbn;
  const int swz = ((nwg & 7) == 0) ? ((bid & 7) * (nwg >> 3) + (bid >> 3)) : bid;
  const int brow = (swz / nbn) << 8;
  const int bcol = (swz % nbn) << 8;

  // staging: 4 chunks/thread/matrix/tile; chunk c = i*512+tid
  // LDS dest f16 = c*8 (lane-linear). Content: row=c>>3, kchunk=(c&7)^(row&7).
  int aglob[4], bglob[4], ldst[4];
#pragma unroll
  for (int i = 0; i < 4; ++i) {
    int c = i * 512 + tid;
    int row = c >> 3;
    int kc = (c & 7) ^ (row & 7);
    ldst[i] = c * 8;
    aglob[i] = (brow + row) * IN_F + kc * 8;
    bglob[i] = (bcol + row) * IN_F + kc * 8;
  }

  // fragment read offsets (f16 index in 16384-tile):
  //   row*64 + (((ks<<2)|hi) ^ (row&7))*8 ; row&7 == l7 for all our rows
  const int abase = (wr * 128 + lo) * 64;   // + mf*1024 + slot
  const int bbase = (wc * 64 + lo) * 64;    // + nf*1024 + slot
  const int slot0 = ((hi) ^ l7) * 8;        // ks=0
  const int slot1 = ((4 + hi) ^ l7) * 8;    // ks=1

  f32x4 acc[8][4] = {};

  // prologue: stage tile 0 -> buf 0
#pragma unroll
  for (int i = 0; i < 4; ++i) gload16(Xh + aglob[i], &As[0][ldst[i]]);
#pragma unroll
  for (int i = 0; i < 4; ++i) gload16(Bm + bglob[i], &Bs[0][ldst[i]]);
  asm volatile("s_waitcnt vmcnt(0)" ::: "memory");
  __builtin_amdgcn_sched_barrier(0);
  __builtin_amdgcn_s_barrier();

  const int NT = IN_F / 64;                 // 64
  for (int kt = 0; kt < NT; ++kt) {
    const f16* A = As[kt & 1];
    const f16* B = Bs[kt & 1];
    f16* An = (f16*)As[(kt & 1) ^ 1];
    f16* Bn = (f16*)Bs[(kt & 1) ^ 1];
    const int kn = (kt + 1) * 64;
    const bool pf = (kt + 1 < NT);

    f16x8 bf[4][2];
    f16x8 af[2][2];

    // ---- phase 1: B-frags (8) + A quad0 (4) | stage A chunks 0,1 of kt+1
#pragma unroll
    for (int nf = 0; nf < 4; ++nf) {
      bf[nf][0] = *(const f16x8*)(B + bbase + nf * 1024 + slot0);
      bf[nf][1] = *(const f16x8*)(B + bbase + nf * 1024 + slot1);
    }
    af[0][0] = *(const f16x8*)(A + abase + 0 * 1024 + slot0);
    af[0][1] = *(const f16x8*)(A + abase + 0 * 1024 + slot1);
    af[1][0] = *(const f16x8*)(A + abase + 1 * 1024 + slot0);
    af[1][1] = *(const f16x8*)(A + abase + 1 * 1024 + slot1);
    if (pf) { gload16(Xh + aglob[0] + kn, An + ldst[0]);
              gload16(Xh + aglob[1] + kn, An + ldst[1]); }
    __builtin_amdgcn_s_barrier();
    __builtin_amdgcn_s_setprio(1);
#pragma unroll
    for (int mm = 0; mm < 2; ++mm)
#pragma unroll
      for (int nf = 0; nf < 4; ++nf) {
        acc[mm][nf] = __builtin_amdgcn_mfma_f32_16x16x32_f16(af[mm][0], bf[nf][0], acc[mm][nf], 0, 0, 0);
        acc[mm][nf] = __builtin_amdgcn_mfma_f32_16x16x32_f16(af[mm][1], bf[nf][1], acc[mm][nf], 0, 0, 0);
      }
    __builtin_amdgcn_s_setprio(0);
    __builtin_amdgcn_s_barrier();

    // ---- phase 2: A quad1 | stage A chunks 2,3
    af[0][0] = *(const f16x8*)(A + abase + 2 * 1024 + slot0);
    af[0][1] = *(const f16x8*)(A + abase + 2 * 1024 + slot1);
    af[1][0] = *(const f16x8*)(A + abase + 3 * 1024 + slot0);
    af[1][1] = *(const f16x8*)(A + abase + 3 * 1024 + slot1);
    if (pf) { gload16(Xh + aglob[2] + kn, An + ldst[2]);
              gload16(Xh + aglob[3] + kn, An + ldst[3]); }
    __builtin_amdgcn_s_barrier();
    __builtin_amdgcn_s_setprio(1);
#pragma unroll
    for (int mm = 0; mm < 2; ++mm)
#pragma unroll
      for (int nf = 0; nf < 4; ++nf) {
        acc[2 + mm][nf] = __builtin_amdgcn_mfma_f32_16x16x32_f16(af[mm][0], bf[nf][0], acc[2 + mm][nf], 0, 0, 0);
        acc[2 + mm][nf] = __builtin_amdgcn_mfma_f32_16x16x32_f16(af[mm][1], bf[nf][1], acc[2 + mm][nf], 0, 0, 0);
      }
    __builtin_amdgcn_s_setprio(0);
    __builtin_amdgcn_s_barrier();

    // ---- phase 3: A quad2 | stage B chunks 0,1
    af[0][0] = *(const f16x8*)(A + abase + 4 * 1024 + slot0);
    af[0][1] = *(const f16x8*)(A + abase + 4 * 1024 + slot1);
    af[1][0] = *(const f16x8*)(A + abase + 5 * 1024 + slot0);
    af[1][1] = *(const f16x8*)(A + abase + 5 * 1024 + slot1);
    if (pf) { gload16(Bm + bglob[0] + kn, Bn + ldst[0]);
              gload16(Bm + bglob[1] + kn, Bn + ldst[1]); }
    __builtin_amdgcn_s_barrier();
    __builtin_amdgcn_s_setprio(1);
#pragma unroll
    for (int mm = 0; mm < 2; ++mm)
#pragma unroll
      for (int nf = 0; nf < 4; ++nf) {
        acc[4 + mm][nf] = __builtin_amdgcn_mfma_f32_16x16x32_f16(af[mm][0], bf[nf][0], acc[4 + mm][nf], 0, 0, 0);
        acc[4 + mm][nf] = __builtin_amdgcn_mfma_f32_16x16x32_f16(af[mm][1], bf[nf][1], acc[4 + mm][nf], 0, 0, 0);
      }
    __builtin_amdgcn_s_setprio(0);
    __builtin_amdgcn_s_barrier();

    // ---- phase 4: A quad3 | stage B chunks 2,3
    af[0][0] = *(const f16x8*)(A + abase + 6 * 1024 + slot0);
    af[0][1] = *(const f16x8*)(A + abase + 6 * 1024 + slot1);
    af[1][0] = *(const f16x8*)(A + abase + 7 * 1024 + slot0);
    af[1][1] = *(const f16x8*)(A + abase + 7 * 1024 + slot1);
    if (pf) { gload16(Bm + bglob[2] + kn, Bn + ldst[2]);
              gload16(Bm + bglob[3] + kn, Bn + ldst[3]); }
    __builtin_amdgcn_s_barrier();
    __builtin_amdgcn_s_setprio(1);
#pragma unroll
    for (int mm = 0; mm < 2; ++mm)
#pragma unroll
      for (int nf = 0; nf < 4; ++nf) {
        acc[6 + mm][nf] = __builtin_amdgcn_mfma_f32_16x16x32_f16(af[mm][0], bf[nf][0], acc[6 + mm][nf], 0, 0, 0);
        acc[6 + mm][nf] = __builtin_amdgcn_mfma_f32_16x16x32_f16(af[mm][1], bf[nf][1], acc[6 + mm][nf], 0, 0, 0);
      }
    __builtin_amdgcn_s_setprio(0);

    // ---- tile boundary: next tile's 16 chunks are the ONLY outstanding loads
    if (pf) {
      asm volatile("s_waitcnt vmcnt(0)" ::: "memory");
      __builtin_amdgcn_sched_barrier(0);
    }
    __builtin_amdgcn_s_barrier();
  }

  // epilogue.  C/D: col = lane&15, row = (lane>>4)*4 + r  (m89-verified)
  const int crow0 = brow + wr * 128 + (hi << 2);
  const int ccol0 = bcol + wc * 64 + lo;
#pragma unroll
  for (int mf = 0; mf < 8; ++mf)
#pragma unroll
    for (int nf = 0; nf < 4; ++nf)
#pragma unroll
      for (int r = 0; r < 4; ++r) {
        float* p = out + (size_t)(crow0 + mf * 16 + r) * OUT_F + (ccol0 + nf * 16);
        if constexpr (STREAM == 0)
          *p = (float)(f16)acc[mf][nf][r];
        else
          *p += acc[mf][nf][r];
      }
}

// ---------------------------------------------------------------------------
// R12 fallback kernel (proven): 128x128, 2-barrier, for odd shapes / small ws.
// ---------------------------------------------------------------------------
template <bool A16, int STREAM>
__global__ __launch_bounds__(256, 2) void gemm_one(
    const float* __restrict__ Xf, const f16* __restrict__ Xh,
    const f16* __restrict__ Bm, float* __restrict__ out, int M) {
  constexpr int LDA = A16 ? 32 : 40;
  __shared__ alignas(16) f16 As[128 * LDA];
  __shared__ alignas(16) f16 Bs[128 * 32];

  const int tid = threadIdx.x, lane = tid & 63, wave = tid >> 6;
  const int wr = wave >> 1, wc = wave & 1;
  const int nbn = OUT_F / 128;
  const int nwg = (int)gridDim.x;
  const int bid = (int)blockIdx.x;
  const int swz = ((nwg & 7) == 0) ? ((bid & 7) * (nwg >> 3) + (bid >> 3)) : bid;
  const int brow = (swz / nbn) << 7;
  const int bcol = (swz % nbn) << 7;

  f32x4 acc[4][4] = {};
  const int srow = tid >> 2, sk = (tid & 3) * 8;
  const f16* gB = Bm + (size_t)(bcol + srow) * IN_F + sk;
  f16* sB = Bs + tid * 8;
  const f16*   gA = A16 ? (Xh + (size_t)(brow + srow) * IN_F + sk) : (const f16*)nullptr;
  const float* gX = A16 ? (const float*)nullptr : (Xf + (size_t)(brow + srow) * IN_F + sk);
  f16* sA  = As + tid * 8;
  f16* sAr = As + srow * LDA + sk;
  const f16* pa = As + (wr * 64 + (lane & 15)) * LDA + (lane >> 4) * 8;
  const f16* pb = Bs + (wc * 64 + (lane & 15)) * 32 + (lane >> 4) * 8;

  for (int k0 = 0; k0 < IN_F; k0 += 32) {
    if constexpr (A16) {
      gload16(gA + k0, sA);
      gload16(gA + k0 + (size_t)64 * IN_F, sA + 2048);
    } else {
      float4 u0 = *(const float4*)(gX + k0);
      float4 u1 = *(const float4*)(gX + k0 + 4);
      float4 v0 = *(const float4*)(gX + k0 + (size_t)64 * IN_F);
      float4 v1 = *(const float4*)(gX + k0 + (size_t)64 * IN_F + 4);
      f16x8 h0, h1;
      h0[0] = (f16)u0.x; h0[1] = (f16)u0.y; h0[2] = (f16)u0.z; h0[3] = (f16)u0.w;
      h0[4] = (f16)u1.x; h0[5] = (f16)u1.y; h0[6] = (f16)u1.z; h0[7] = (f16)u1.w;
      h1[0] = (f16)v0.x; h1[1] = (f16)v0.y; h1[2] = (f16)v0.z; h1[3] = (f16)v0.w;
      h1[4] = (f16)v1.x; h1[5] = (f16)v1.y; h1[6] = (f16)v1.z; h1[7] = (f16)v1.w;
      *(f16x8*)sAr = h0;
      *(f16x8*)(sAr + 64 * LDA) = h1;
    }
    gload16(gB + k0, sB);
    gload16(gB + k0 + (size_t)64 * IN_F, sB + 2048);
    __syncthreads();
    f16x8 af[4], bfr[4];
#pragma unroll
    for (int m = 0; m < 4; ++m) af[m] = *(const f16x8*)(pa + m * 16 * LDA);
#pragma unroll
    for (int n = 0; n < 4; ++n) bfr[n] = *(const f16x8*)(pb + n * 512);
#pragma unroll
    for (int m = 0; m < 4; ++m)
#pragma unroll
      for (int n = 0; n < 4; ++n)
        acc[m][n] = __builtin_amdgcn_mfma_f32_16x16x32_f16(af[m], bfr[n], acc[m][n], 0, 0, 0);
    __syncthreads();
  }
  const int crow0 = brow + wr * 64 + ((lane >> 4) << 2);
  const int ccol0 = bcol + wc * 64 + (lane & 15);
#pragma unroll
  for (int m = 0; m < 4; ++m)
#pragma unroll
    for (int n = 0; n < 4; ++n)
#pragma unroll
      for (int r = 0; r < 4; ++r) {
        float* p = out + (size_t)(crow0 + m * 16 + r) * OUT_F + (ccol0 + n * 16);
        if constexpr (STREAM == 0) *p = (float)(f16)acc[m][n][r];
        else *p += acc[m][n][r];
      }
}

// ---------------------------------------------------------------------------
extern "C" void kernel_launch(void* const* d_in, const int* in_sizes, int n_in,
                              void* d_out, int out_size, void* d_ws, size_t ws_size,
                              hipStream_t stream) {
  const float* x    = (const float*)d_in[0];
  const float* W    = (const float*)d_in[1];
  const float* vals = (const float*)d_in[2];
  const int*   rows = (const int*)d_in[3];
  const int*   cols = (const int*)d_in[4];
  float*       out  = (float*)d_out;

  const i64 total_x = (i64)in_sizes[0];
  const int M   = (int)(total_x / IN_F);            // 8192
  const int nnz = in_sizes[2];
  if (M <= 0 || M % 128 != 0) return;

  const size_t whb = (size_t)OUT_F * IN_F * 2;      // 32 MB
  const size_t xhb = (size_t)M * IN_F * 2;          // 64 MB

  if (ws_size >= xhb + 2 * whb) {
    f16* xh  = (f16*)d_ws;
    f16* wh  = (f16*)((char*)d_ws + xhb);
    f16* woh = (f16*)((char*)d_ws + xhb + whb);
    cvt_f32_f16<<<2048, 256, 0, stream>>>(x, xh, total_x / 8);
    cvt_f32_f16<<<2048, 256, 0, stream>>>(W, wh, (i64)OUT_F * IN_F / 8);
    zero32<<<2048, 256, 0, stream>>>((u32*)woh, (i64)(whb / 4));
    scatter_woh<<<(nnz + 255) / 256, 256, 0, stream>>>(vals, rows, cols, woh, nnz);
    if (M % 256 == 0) {
      const int grid = (M / 256) * (OUT_F / 256);   // 512
      gemm_256<0><<<grid, 512, 0, stream>>>(xh, wh, out, M);
      gemm_256<1><<<grid, 512, 0, stream>>>(xh, woh, out, M);
    } else {
      const int grid = (M / 128) * (OUT_F / 128);
      gemm_one<true, 0><<<grid, 256, 0, stream>>>(nullptr, xh, wh, out, M);
      gemm_one<true, 1><<<grid, 256, 0, stream>>>(nullptr, xh, woh, out, M);
    }
  } else if (ws_size >= 2 * whb) {
    f16* wh  = (f16*)d_ws;
    f16* woh = (f16*)((char*)d_ws + whb);
    cvt_f32_f16<<<2048, 256, 0, stream>>>(W, wh, (i64)OUT_F * IN_F / 8);
    zero32<<<2048, 256, 0, stream>>>((u32*)woh, (i64)(whb / 4));
    scatter_woh<<<(nnz + 255) / 256, 256, 0, stream>>>(vals, rows, cols, woh, nnz);
    const int grid = (M / 128) * (OUT_F / 128);
    gemm_one<false, 0><<<grid, 256, 0, stream>>>(x, nullptr, wh, out, M);
    gemm_one<false, 1><<<grid, 256, 0, stream>>>(x, nullptr, woh, out, M);
  }
}

// Round 14
// 584.085 us; speedup vs baseline: 39.2376x; 1.1247x over previous
//
#include <hip/hip_runtime.h>

typedef _Float16 f16;
typedef unsigned short u16;
typedef unsigned int u32;
typedef long long i64;
typedef __attribute__((ext_vector_type(8))) _Float16 f16x8;
typedef __attribute__((ext_vector_type(4))) float f32x4;

#define IN_F 4096
#define OUT_F 4096

__device__ __forceinline__ void gload16(const f16* g, f16* l) {
  __builtin_amdgcn_global_load_lds(
      (const __attribute__((address_space(1))) void*)g,
      (__attribute__((address_space(3))) void*)l, 16, 0, 0);
}

// ---------------------------------------------------------------------------
// prep kernels
// ---------------------------------------------------------------------------
__global__ __launch_bounds__(256) void cvt_f32_f16(
    const float* __restrict__ in, f16* __restrict__ out, i64 n8) {
  i64 s = (i64)gridDim.x * blockDim.x;
  for (i64 j = (i64)blockIdx.x * blockDim.x + threadIdx.x; j < n8; j += s) {
    float4 a = ((const float4*)in)[2 * j];
    float4 b = ((const float4*)in)[2 * j + 1];
    f16x8 o;
    o[0] = (f16)a.x; o[1] = (f16)a.y; o[2] = (f16)a.z; o[3] = (f16)a.w;
    o[4] = (f16)b.x; o[5] = (f16)b.y; o[6] = (f16)b.z; o[7] = (f16)b.w;
    ((f16x8*)out)[j] = o;
  }
}

__global__ __launch_bounds__(256) void zero32(u32* __restrict__ p, i64 n) {
  i64 s = (i64)gridDim.x * blockDim.x;
  for (i64 j = (i64)blockIdx.x * blockDim.x + threadIdx.x; j < n; j += s) p[j] = 0u;
}

__global__ __launch_bounds__(256) void scatter_woh(
    const float* __restrict__ vals, const int* __restrict__ rows,
    const int* __restrict__ cols, f16* __restrict__ woh, int nnz) {
  int i = blockIdx.x * blockDim.x + threadIdx.x;
  if (i >= nnz) return;
  int r = rows[i], c = cols[i];
  if (r < 0 || r >= OUT_F || c < 0 || c >= IN_F) return;
  float v = vals[i];
  size_t idx = (size_t)r * IN_F + c;
  u32* p = (u32*)woh + (idx >> 1);
  u32 sh = (u32)(idx & 1) * 16u;
  union { f16 h; u16 u; } cv;
  u32 old = *p;
  while (true) {
    u32 assumed = old;
    cv.u = (u16)((assumed >> sh) & 0xFFFFu);
    float cur = (float)cv.h;
    cv.h = (f16)(cur + v);
    u32 nw = (assumed & ~(0xFFFFu << sh)) | ((u32)cv.u << sh);
    old = atomicCAS(p, assumed, nw);
    if (old == assumed) break;
  }
}

// ---------------------------------------------------------------------------
// 256x256 8-phase GEMM, T2 swizzle + T3 + T4 COUNTED vmcnt + T5 setprio.
// Stage order per K-tile: ph1 B{0,1}, ph2 B{2,3}, ph3 A{0,2}, ph4 A{1,3}.
// Waits: ph2-end vmcnt(pf?4:0) gates A-chunks{1,3}; ph4-end vmcnt(2) gates
// B-all + A{0,2} for next iter (leaves A{1,3} in flight across the boundary).
// Per-wave vmcnt + identical issue order in all waves + barrier => cross-wave
// visibility guarantee.
// ---------------------------------------------------------------------------
template <int STREAM>
__global__ __launch_bounds__(512, 2) void gemm_256(
    const f16* __restrict__ Xh, const f16* __restrict__ Bm,
    float* __restrict__ out, int M) {
  __shared__ alignas(16) f16 As[2][16384];
  __shared__ alignas(16) f16 Bs[2][16384];

  const int tid = threadIdx.x;
  const int lane = tid & 63;
  const int wave = tid >> 6;
  const int wr = wave >> 2;         // 0..1  (M half)
  const int wc = wave & 3;          // 0..3  (N quarter)
  const int lo = lane & 15, hi = lane >> 4, l7 = lane & 7;

  const int bid = (int)blockIdx.x;
  const int nbn = OUT_F / 256;                      // 16
  const int nwg = (M / 256) * nbn;
  const int swz = ((nwg & 7) == 0) ? ((bid & 7) * (nwg >> 3) + (bid >> 3)) : bid;
  const int brow = (swz / nbn) << 8;
  const int bcol = (swz % nbn) << 8;

  // staging chunks: c = i*512+tid; LDS dest = c*8 (lane-linear);
  // source row = c>>3, kchunk = (c&7)^(row&7)  [T2: pre-swizzled global src]
  int aglob[4], bglob[4], ldst[4];
#pragma unroll
  for (int i = 0; i < 4; ++i) {
    int c = i * 512 + tid;
    int row = c >> 3;
    int kc = (c & 7) ^ (row & 7);
    ldst[i] = c * 8;
    aglob[i] = (brow + row) * IN_F + kc * 8;
    bglob[i] = (bcol + row) * IN_F + kc * 8;
  }

  // fragment read offsets: row*64 + (((ks<<2)|hi) ^ (row&7))*8, row&7 == l7
  const int abase = (wr * 128 + lo) * 64;   // + mf*1024 + slot
  const int bbase = (wc * 64 + lo) * 64;    // + nf*1024 + slot
  const int slot0 = ((hi) ^ l7) * 8;        // ks=0
  const int slot1 = ((4 + hi) ^ l7) * 8;    // ks=1

  f32x4 acc[8][4] = {};

  // prologue: stage tile 0 -> buf 0 in steady-state order
  gload16(Bm + bglob[0], &Bs[0][ldst[0]]);
  gload16(Bm + bglob[1], &Bs[0][ldst[1]]);
  gload16(Bm + bglob[2], &Bs[0][ldst[2]]);
  gload16(Bm + bglob[3], &Bs[0][ldst[3]]);
  gload16(Xh + aglob[0], &As[0][ldst[0]]);
  gload16(Xh + aglob[2], &As[0][ldst[2]]);
  gload16(Xh + aglob[1], &As[0][ldst[1]]);
  gload16(Xh + aglob[3], &As[0][ldst[3]]);
  asm volatile("s_waitcnt vmcnt(2)" ::: "memory");  // B0-3,A0,A2 landed; A1,A3 fly
  __builtin_amdgcn_sched_barrier(0);
  __builtin_amdgcn_s_barrier();

  const int NT = IN_F / 64;                 // 64
  for (int kt = 0; kt < NT; ++kt) {
    const f16* A = As[kt & 1];
    const f16* B = Bs[kt & 1];
    f16* An = (f16*)As[(kt & 1) ^ 1];
    f16* Bn = (f16*)Bs[(kt & 1) ^ 1];
    const int kn = (kt + 1) * 64;
    const bool pf = (kt + 1 < NT);

    f16x8 bf[4][2];
    f16x8 af[2][2];

    // ---- phase 1: read B-all + A mf0,1 | stage B chunks 0,1
#pragma unroll
    for (int nf = 0; nf < 4; ++nf) {
      bf[nf][0] = *(const f16x8*)(B + bbase + nf * 1024 + slot0);
      bf[nf][1] = *(const f16x8*)(B + bbase + nf * 1024 + slot1);
    }
    af[0][0] = *(const f16x8*)(A + abase + 0 * 1024 + slot0);
    af[0][1] = *(const f16x8*)(A + abase + 0 * 1024 + slot1);
    af[1][0] = *(const f16x8*)(A + abase + 1 * 1024 + slot0);
    af[1][1] = *(const f16x8*)(A + abase + 1 * 1024 + slot1);
    if (pf) { gload16(Bm + bglob[0] + kn, Bn + ldst[0]);
              gload16(Bm + bglob[1] + kn, Bn + ldst[1]); }
    __builtin_amdgcn_s_barrier();
    __builtin_amdgcn_s_setprio(1);
#pragma unroll
    for (int mm = 0; mm < 2; ++mm)
#pragma unroll
      for (int nf = 0; nf < 4; ++nf) {
        acc[mm][nf] = __builtin_amdgcn_mfma_f32_16x16x32_f16(af[mm][0], bf[nf][0], acc[mm][nf], 0, 0, 0);
        acc[mm][nf] = __builtin_amdgcn_mfma_f32_16x16x32_f16(af[mm][1], bf[nf][1], acc[mm][nf], 0, 0, 0);
      }
    __builtin_amdgcn_s_setprio(0);
    __builtin_amdgcn_s_barrier();

    // ---- phase 2: read A mf2,3 | stage B chunks 2,3 | gate A{1,3}
    af[0][0] = *(const f16x8*)(A + abase + 2 * 1024 + slot0);
    af[0][1] = *(const f16x8*)(A + abase + 2 * 1024 + slot1);
    af[1][0] = *(const f16x8*)(A + abase + 3 * 1024 + slot0);
    af[1][1] = *(const f16x8*)(A + abase + 3 * 1024 + slot1);
    if (pf) { gload16(Bm + bglob[2] + kn, Bn + ldst[2]);
              gload16(Bm + bglob[3] + kn, Bn + ldst[3]); }
    if (pf) asm volatile("s_waitcnt vmcnt(4)" ::: "memory");
    else    asm volatile("s_waitcnt vmcnt(0)" ::: "memory");
    __builtin_amdgcn_sched_barrier(0);
    __builtin_amdgcn_s_barrier();
    __builtin_amdgcn_s_setprio(1);
#pragma unroll
    for (int mm = 0; mm < 2; ++mm)
#pragma unroll
      for (int nf = 0; nf < 4; ++nf) {
        acc[2 + mm][nf] = __builtin_amdgcn_mfma_f32_16x16x32_f16(af[mm][0], bf[nf][0], acc[2 + mm][nf], 0, 0, 0);
        acc[2 + mm][nf] = __builtin_amdgcn_mfma_f32_16x16x32_f16(af[mm][1], bf[nf][1], acc[2 + mm][nf], 0, 0, 0);
      }
    __builtin_amdgcn_s_setprio(0);
    __builtin_amdgcn_s_barrier();

    // ---- phase 3: read A mf4,5 | stage A chunks 0,2
    af[0][0] = *(const f16x8*)(A + abase + 4 * 1024 + slot0);
    af[0][1] = *(const f16x8*)(A + abase + 4 * 1024 + slot1);
    af[1][0] = *(const f16x8*)(A + abase + 5 * 1024 + slot0);
    af[1][1] = *(const f16x8*)(A + abase + 5 * 1024 + slot1);
    if (pf) { gload16(Xh + aglob[0] + kn, An + ldst[0]);
              gload16(Xh + aglob[2] + kn, An + ldst[2]); }
    __builtin_amdgcn_s_barrier();
    __builtin_amdgcn_s_setprio(1);
#pragma unroll
    for (int mm = 0; mm < 2; ++mm)
#pragma unroll
      for (int nf = 0; nf < 4; ++nf) {
        acc[4 + mm][nf] = __builtin_amdgcn_mfma_f32_16x16x32_f16(af[mm][0], bf[nf][0], acc[4 + mm][nf], 0, 0, 0);
        acc[4 + mm][nf] = __builtin_amdgcn_mfma_f32_16x16x32_f16(af[mm][1], bf[nf][1], acc[4 + mm][nf], 0, 0, 0);
      }
    __builtin_amdgcn_s_setprio(0);
    __builtin_amdgcn_s_barrier();

    // ---- phase 4: read A mf6,7 | stage A chunks 1,3 | gate next ph1/ph2
    af[0][0] = *(const f16x8*)(A + abase + 6 * 1024 + slot0);
    af[0][1] = *(const f16x8*)(A + abase + 6 * 1024 + slot1);
    af[1][0] = *(const f16x8*)(A + abase + 7 * 1024 + slot0);
    af[1][1] = *(const f16x8*)(A + abase + 7 * 1024 + slot1);
    if (pf) { gload16(Xh + aglob[1] + kn, An + ldst[1]);
              gload16(Xh + aglob[3] + kn, An + ldst[3]); }
    if (pf) {
      asm volatile("s_waitcnt vmcnt(2)" ::: "memory");  // A{1,3} stay in flight
      __builtin_amdgcn_sched_barrier(0);
    }
    __builtin_amdgcn_s_barrier();
    __builtin_amdgcn_s_setprio(1);
#pragma unroll
    for (int mm = 0; mm < 2; ++mm)
#pragma unroll
      for (int nf = 0; nf < 4; ++nf) {
        acc[6 + mm][nf] = __builtin_amdgcn_mfma_f32_16x16x32_f16(af[mm][0], bf[nf][0], acc[6 + mm][nf], 0, 0, 0);
        acc[6 + mm][nf] = __builtin_amdgcn_mfma_f32_16x16x32_f16(af[mm][1], bf[nf][1], acc[6 + mm][nf], 0, 0, 0);
      }
    __builtin_amdgcn_s_setprio(0);
    __builtin_amdgcn_s_barrier();
  }

  // epilogue.  C/D: col = lane&15, row = (lane>>4)*4 + r
  const int crow0 = brow + wr * 128 + (hi << 2);
  const int ccol0 = bcol + wc * 64 + lo;
#pragma unroll
  for (int mf = 0; mf < 8; ++mf)
#pragma unroll
    for (int nf = 0; nf < 4; ++nf)
#pragma unroll
      for (int r = 0; r < 4; ++r) {
        float* p = out + (size_t)(crow0 + mf * 16 + r) * OUT_F + (ccol0 + nf * 16);
        if constexpr (STREAM == 0)
          *p = (float)(f16)acc[mf][nf][r];
        else
          *p += acc[mf][nf][r];
      }
}

// ---------------------------------------------------------------------------
// R12 fallback (proven): 128x128, 2-barrier
// ---------------------------------------------------------------------------
template <bool A16, int STREAM>
__global__ __launch_bounds__(256, 2) void gemm_one(
    const float* __restrict__ Xf, const f16* __restrict__ Xh,
    const f16* __restrict__ Bm, float* __restrict__ out, int M) {
  constexpr int LDA = A16 ? 32 : 40;
  __shared__ alignas(16) f16 As[128 * LDA];
  __shared__ alignas(16) f16 Bs[128 * 32];

  const int tid = threadIdx.x, lane = tid & 63, wave = tid >> 6;
  const int wr = wave >> 1, wc = wave & 1;
  const int nbn = OUT_F / 128;
  const int nwg = (int)gridDim.x;
  const int bid = (int)blockIdx.x;
  const int swz = ((nwg & 7) == 0) ? ((bid & 7) * (nwg >> 3) + (bid >> 3)) : bid;
  const int brow = (swz / nbn) << 7;
  const int bcol = (swz % nbn) << 7;

  f32x4 acc[4][4] = {};
  const int srow = tid >> 2, sk = (tid & 3) * 8;
  const f16* gB = Bm + (size_t)(bcol + srow) * IN_F + sk;
  f16* sB = Bs + tid * 8;
  const f16*   gA = A16 ? (Xh + (size_t)(brow + srow) * IN_F + sk) : (const f16*)nullptr;
  const float* gX = A16 ? (const float*)nullptr : (Xf + (size_t)(brow + srow) * IN_F + sk);
  f16* sA  = As + tid * 8;
  f16* sAr = As + srow * LDA + sk;
  const f16* pa = As + (wr * 64 + (lane & 15)) * LDA + (lane >> 4) * 8;
  const f16* pb = Bs + (wc * 64 + (lane & 15)) * 32 + (lane >> 4) * 8;

  for (int k0 = 0; k0 < IN_F; k0 += 32) {
    if constexpr (A16) {
      gload16(gA + k0, sA);
      gload16(gA + k0 + (size_t)64 * IN_F, sA + 2048);
    } else {
      float4 u0 = *(const float4*)(gX + k0);
      float4 u1 = *(const float4*)(gX + k0 + 4);
      float4 v0 = *(const float4*)(gX + k0 + (size_t)64 * IN_F);
      float4 v1 = *(const float4*)(gX + k0 + (size_t)64 * IN_F + 4);
      f16x8 h0, h1;
      h0[0] = (f16)u0.x; h0[1] = (f16)u0.y; h0[2] = (f16)u0.z; h0[3] = (f16)u0.w;
      h0[4] = (f16)u1.x; h0[5] = (f16)u1.y; h0[6] = (f16)u1.z; h0[7] = (f16)u1.w;
      h1[0] = (f16)v0.x; h1[1] = (f16)v0.y; h1[2] = (f16)v0.z; h1[3] = (f16)v0.w;
      h1[4] = (f16)v1.x; h1[5] = (f16)v1.y; h1[6] = (f16)v1.z; h1[7] = (f16)v1.w;
      *(f16x8*)sAr = h0;
      *(f16x8*)(sAr + 64 * LDA) = h1;
    }
    gload16(gB + k0, sB);
    gload16(gB + k0 + (size_t)64 * IN_F, sB + 2048);
    __syncthreads();
    f16x8 af[4], bfr[4];
#pragma unroll
    for (int m = 0; m < 4; ++m) af[m] = *(const f16x8*)(pa + m * 16 * LDA);
#pragma unroll
    for (int n = 0; n < 4; ++n) bfr[n] = *(const f16x8*)(pb + n * 512);
#pragma unroll
    for (int m = 0; m < 4; ++m)
#pragma unroll
      for (int n = 0; n < 4; ++n)
        acc[m][n] = __builtin_amdgcn_mfma_f32_16x16x32_f16(af[m], bfr[n], acc[m][n], 0, 0, 0);
    __syncthreads();
  }
  const int crow0 = brow + wr * 64 + ((lane >> 4) << 2);
  const int ccol0 = bcol + wc * 64 + (lane & 15);
#pragma unroll
  for (int m = 0; m < 4; ++m)
#pragma unroll
    for (int n = 0; n < 4; ++n)
#pragma unroll
      for (int r = 0; r < 4; ++r) {
        float* p = out + (size_t)(crow0 + m * 16 + r) * OUT_F + (ccol0 + n * 16);
        if constexpr (STREAM == 0) *p = (float)(f16)acc[m][n][r];
        else *p += acc[m][n][r];
      }
}

// ---------------------------------------------------------------------------
extern "C" void kernel_launch(void* const* d_in, const int* in_sizes, int n_in,
                              void* d_out, int out_size, void* d_ws, size_t ws_size,
                              hipStream_t stream) {
  const float* x    = (const float*)d_in[0];
  const float* W    = (const float*)d_in[1];
  const float* vals = (const float*)d_in[2];
  const int*   rows = (const int*)d_in[3];
  const int*   cols = (const int*)d_in[4];
  float*       out  = (float*)d_out;

  const i64 total_x = (i64)in_sizes[0];
  const int M   = (int)(total_x / IN_F);            // 8192
  const int nnz = in_sizes[2];
  if (M <= 0 || M % 128 != 0) return;

  const size_t whb = (size_t)OUT_F * IN_F * 2;      // 32 MB
  const size_t xhb = (size_t)M * IN_F * 2;          // 64 MB

  if (ws_size >= xhb + 2 * whb) {
    f16* xh  = (f16*)d_ws;
    f16* wh  = (f16*)((char*)d_ws + xhb);
    f16* woh = (f16*)((char*)d_ws + xhb + whb);
    cvt_f32_f16<<<2048, 256, 0, stream>>>(x, xh, total_x / 8);
    cvt_f32_f16<<<2048, 256, 0, stream>>>(W, wh, (i64)OUT_F * IN_F / 8);
    zero32<<<2048, 256, 0, stream>>>((u32*)woh, (i64)(whb / 4));
    scatter_woh<<<(nnz + 255) / 256, 256, 0, stream>>>(vals, rows, cols, woh, nnz);
    if (M % 256 == 0) {
      const int grid = (M / 256) * (OUT_F / 256);   // 512
      gemm_256<0><<<grid, 512, 0, stream>>>(xh, wh, out, M);
      gemm_256<1><<<grid, 512, 0, stream>>>(xh, woh, out, M);
    } else {
      const int grid = (M / 128) * (OUT_F / 128);
      gemm_one<true, 0><<<grid, 256, 0, stream>>>(nullptr, xh, wh, out, M);
      gemm_one<true, 1><<<grid, 256, 0, stream>>>(nullptr, xh, woh, out, M);
    }
  } else if (ws_size >= 2 * whb) {
    f16* wh  = (f16*)d_ws;
    f16* woh = (f16*)((char*)d_ws + whb);
    cvt_f32_f16<<<2048, 256, 0, stream>>>(W, wh, (i64)OUT_F * IN_F / 8);
    zero32<<<2048, 256, 0, stream>>>((u32*)woh, (i64)(whb / 4));
    scatter_woh<<<(nnz + 255) / 256, 256, 0, stream>>>(vals, rows, cols, woh, nnz);
    const int grid = (M / 128) * (OUT_F / 128);
    gemm_one<false, 0><<<grid, 256, 0, stream>>>(x, nullptr, wh, out, M);
    gemm_one<false, 1><<<grid, 256, 0, stream>>>(x, nullptr, woh, out, M);
  }
}